// Round 1
// baseline (2195.629 us; speedup 1.0000x reference)
//
#include <hip/hip_runtime.h>
#include <cstdint>
#include <cstddef>

static constexpr int Bb = 8;
static constexpr int Nn = 2048;
static constexpr int Kn = 20;
static constexpr float EPSV = 1e-5f;

// ---------------------------------------------------------------- utilities

__global__ void zero_kernel(float* __restrict__ p, int n) {
    int i = blockIdx.x * 256 + threadIdx.x;
    if (i < n) p[i] = 0.f;
}

__global__ void sqnorm_kernel(const float* __restrict__ x, float* __restrict__ xx, int C) {
    int i = blockIdx.x * 256 + threadIdx.x;   // grid sized exactly B*N
    const float* xr = x + (size_t)i * C;
    float s = 0.f;
    for (int c = 0; c < C; ++c) { float v = xr[c]; s += v * v; }
    xx[i] = s;
}

// out[c*R + r] = in[r*Cc + c]   (small matrices, once per launch)
__global__ void transpose_kernel(const float* __restrict__ in, float* __restrict__ out,
                                 int R, int Cc) {
    int i = blockIdx.x * 256 + threadIdx.x;
    if (i < R * Cc) {
        int r = i / Cc, c = i % Cc;
        out[(size_t)c * R + r] = in[i];
    }
}

// ------------------------------------------------ pairwise sq-dist (tiled gram)

template<int C>
__global__ void gram_dist_kernel(const float* __restrict__ x, const float* __restrict__ xx,
                                 float* __restrict__ dist, int b0, size_t dstride) {
    const int b = b0 + blockIdx.z;
    const int i0 = blockIdx.y * 64, j0 = blockIdx.x * 64;
    const int tid = threadIdx.x;
    const int tx = tid & 15, ty = tid >> 4;
    __shared__ float As[64][17], Bs[64][17];
    float acc[4][4] = {};
    const float* xb = x + (size_t)b * Nn * C;
    for (int c0 = 0; c0 < C; c0 += 16) {
#pragma unroll
        for (int q = 0; q < 4; ++q) {
            int e = tid + q * 256;
            int r = e >> 4, c = e & 15;
            float av = 0.f, bv = 0.f;
            if (c0 + c < C) {
                av = xb[(size_t)(i0 + r) * C + (c0 + c)];
                bv = xb[(size_t)(j0 + r) * C + (c0 + c)];
            }
            As[r][c] = av;
            Bs[r][c] = bv;
        }
        __syncthreads();
#pragma unroll
        for (int cc = 0; cc < 16; ++cc) {
            float av[4], bv[4];
#pragma unroll
            for (int u = 0; u < 4; ++u) av[u] = As[ty * 4 + u][cc];
#pragma unroll
            for (int v = 0; v < 4; ++v) bv[v] = Bs[tx * 4 + v][cc];
#pragma unroll
            for (int u = 0; u < 4; ++u)
#pragma unroll
                for (int v = 0; v < 4; ++v)
                    acc[u][v] = fmaf(av[u], bv[v], acc[u][v]);
        }
        __syncthreads();
    }
    const float* xxb = xx + (size_t)b * Nn;
    float xi[4], xj[4];
#pragma unroll
    for (int u = 0; u < 4; ++u) xi[u] = xxb[i0 + ty * 4 + u];
#pragma unroll
    for (int v = 0; v < 4; ++v) xj[v] = xxb[j0 + tx * 4 + v];
    float* db = dist + (size_t)blockIdx.z * dstride;
#pragma unroll
    for (int u = 0; u < 4; ++u)
#pragma unroll
        for (int v = 0; v < 4; ++v)
            db[(size_t)(i0 + ty * 4 + u) * Nn + (j0 + tx * 4 + v)] =
                xi[u] + xj[v] - 2.f * acc[u][v];
}

// ------------------------------------------------------- top-k (k=20 smallest)

__global__ void topk_kernel(const float* __restrict__ dist, int* __restrict__ idxo,
                            int b0, size_t dstride) {
    const int lin = blockIdx.x;
    const int bz = lin >> 11;        // / N
    const int i = lin & (Nn - 1);
    const int b = b0 + bz;
    const float* dr = dist + (size_t)bz * dstride + (size_t)i * Nn;
    const int tid = threadIdx.x;
    float v[8];
#pragma unroll
    for (int m = 0; m < 8; ++m) v[m] = dr[tid + (m << 8)];
    unsigned mask = 0;
    __shared__ float swv[4];
    __shared__ int swi[4];
    __shared__ int sbj;
    int* orow = idxo + ((size_t)b * Nn + i) * Kn;
    for (int t = 0; t < Kn; ++t) {
        float bv = 3e38f; int bj = Nn;
#pragma unroll
        for (int m = 0; m < 8; ++m) {
            int j = tid + (m << 8);
            bool live = ((mask >> m) & 1u) == 0u;
            if (live && (v[m] < bv || (v[m] == bv && j < bj))) { bv = v[m]; bj = j; }
        }
#pragma unroll
        for (int off = 32; off > 0; off >>= 1) {
            float ov = __shfl_down(bv, off);
            int oj = __shfl_down(bj, off);
            if (ov < bv || (ov == bv && oj < bj)) { bv = ov; bj = oj; }
        }
        if ((tid & 63) == 0) { swv[tid >> 6] = bv; swi[tid >> 6] = bj; }
        __syncthreads();
        if (tid == 0) {
            float fb = swv[0]; int fj = swi[0];
#pragma unroll
            for (int w = 1; w < 4; ++w)
                if (swv[w] < fb || (swv[w] == fb && swi[w] < fj)) { fb = swv[w]; fj = swi[w]; }
            sbj = fj;
            orow[t] = fj;
        }
        __syncthreads();
        int win = sbj;
        if (tid == (win & 255)) mask |= (1u << (win >> 8));
    }
}

// ------------------------------------- per-point projections Z1=X Wl^T, Z2=X Wr^T

template<int C, int O>
__global__ void z_kernel(const float* __restrict__ x, const float* __restrict__ wt,
                         float* __restrict__ z1, float* __restrict__ z2) {
    constexpr int TP = 16;
    constexpr int G = 256 / O;
    constexpr int PP = TP / G;
    const int p0 = blockIdx.x * TP;
    const int tid = threadIdx.x;
    const int oo = tid % O;
    const int g = tid / O;
    __shared__ float xs[TP][(C < 4) ? 4 : C];
    for (int e = tid; e < TP * C; e += 256) {
        int p = e / C, c = e % C;
        xs[p][c] = x[(size_t)(p0 + p) * C + c];
    }
    __syncthreads();
    float a1[PP], a2[PP];
#pragma unroll
    for (int p = 0; p < PP; ++p) { a1[p] = 0.f; a2[p] = 0.f; }
    if constexpr (C % 4 == 0) {
        for (int c = 0; c < C; c += 4) {
            float w1[4], w2[4];
#pragma unroll
            for (int q = 0; q < 4; ++q) {
                w1[q] = wt[(size_t)(c + q) * O + oo];
                w2[q] = wt[(size_t)(C + c + q) * O + oo];
            }
#pragma unroll
            for (int p = 0; p < PP; ++p) {
                const float4 xv = *(const float4*)(&xs[g * PP + p][c]);
                a1[p] = fmaf(xv.w, w1[3], fmaf(xv.z, w1[2], fmaf(xv.y, w1[1], fmaf(xv.x, w1[0], a1[p]))));
                a2[p] = fmaf(xv.w, w2[3], fmaf(xv.z, w2[2], fmaf(xv.y, w2[1], fmaf(xv.x, w2[0], a2[p]))));
            }
        }
    } else {
        for (int c = 0; c < C; ++c) {
            float w1 = wt[(size_t)c * O + oo];
            float w2 = wt[(size_t)(C + c) * O + oo];
#pragma unroll
            for (int p = 0; p < PP; ++p) {
                float xv = xs[g * PP + p][c];
                a1[p] = fmaf(xv, w1, a1[p]);
                a2[p] = fmaf(xv, w2, a2[p]);
            }
        }
    }
#pragma unroll
    for (int p = 0; p < PP; ++p) {
        size_t row = (size_t)(p0 + g * PP + p) * O + oo;
        z1[row] = a1[p];
        z2[row] = a2[p];
    }
}

// -------------------- gather edges, max/min over k + BN partial sums (per channel)

template<int O>
__global__ void edge_stats_kernel(const float* __restrict__ z1, const float* __restrict__ z2,
                                  const int* __restrict__ idx,
                                  float* __restrict__ vmax, float* __restrict__ vmin,
                                  float* __restrict__ ssum, float* __restrict__ ssq) {
    constexpr int G = 256 / O;
    constexpr int KK = Kn / G;          // 20 / {1,2,4}
    const int bi = blockIdx.x;          // 0 .. B*N-1
    const int b = bi >> 11;
    const int tid = threadIdx.x;
    const int oo = tid % O;
    const int g = tid / O;
    __shared__ int jl[Kn];
    if (tid < Kn) jl[tid] = idx[(size_t)bi * Kn + tid];
    __syncthreads();
    const float zi1 = z1[(size_t)bi * O + oo];
    const float a = z2[(size_t)bi * O + oo] - zi1;
    float mx = -3e38f, mn = 3e38f, s = 0.f, s2 = 0.f;
    for (int kk = 0; kk < KK; ++kk) {
        int j = jl[g * KK + kk];
        float v = z1[((size_t)b * Nn + j) * O + oo] + a;
        mx = fmaxf(mx, v);
        mn = fminf(mn, v);
        s += v;
        s2 = fmaf(v, v, s2);
    }
    if constexpr (G > 1) {
        __shared__ float smx[256], smn[256], ssm[256], sqq[256];
        smx[tid] = mx; smn[tid] = mn; ssm[tid] = s; sqq[tid] = s2;
        __syncthreads();
        if (tid < O) {
#pragma unroll
            for (int gg = 1; gg < G; ++gg) {
                mx = fmaxf(mx, smx[gg * O + oo]);
                mn = fminf(mn, smn[gg * O + oo]);
                s += ssm[gg * O + oo];
                s2 += sqq[gg * O + oo];
            }
        }
    }
    if (tid < O) {
        vmax[(size_t)bi * O + oo] = mx;
        vmin[(size_t)bi * O + oo] = mn;
        int slot = bi & 63;
        atomicAdd(&ssum[slot * O + oo], s);
        atomicAdd(&ssq[slot * O + oo], s2);
    }
}

__global__ void bn_finalize_kernel(const float* __restrict__ ssum, const float* __restrict__ ssq,
                                   const float* __restrict__ gamma, const float* __restrict__ beta,
                                   float* __restrict__ scale, float* __restrict__ shift, int O) {
    int o = threadIdx.x;
    if (o >= O) return;
    float s = 0.f, q = 0.f;
    for (int sl = 0; sl < 64; ++sl) { s += ssum[sl * O + o]; q += ssq[sl * O + o]; }
    const float cnt = (float)Bb * (float)Nn * (float)Kn;
    float mu = s / cnt;
    float var = q / cnt - mu * mu;
    float sc = gamma[o] / sqrtf(var + EPSV);
    scale[o] = sc;
    shift[o] = beta[o] - mu * sc;
}

__global__ void apply_kernel(const float* __restrict__ vmax, const float* __restrict__ vmin,
                             const float* __restrict__ scale, const float* __restrict__ shift,
                             float* __restrict__ xout, int O, int total) {
    int i = blockIdx.x * 256 + threadIdx.x;
    if (i >= total) return;
    int o = i % O;
    float sc = scale[o];
    float v = (sc >= 0.f) ? vmax[i] : vmin[i];   // max/min commute with monotone affine
    xout[i] = fmaxf(fmaf(v, sc, shift[o]), 0.f);
}

// ------------------------------------------------------- global max+mean pool

__global__ void pool_kernel(const float* __restrict__ x1, const float* __restrict__ x2,
                            const float* __restrict__ x3, const float* __restrict__ x4,
                            float* __restrict__ gv) {
    int blk = blockIdx.x;           // 64 blocks: b(8) x chunk(8)
    int b = blk >> 3, ch = blk & 7;
    int cl = threadIdx.x & 63, ng = threadIdx.x >> 6;
    const float* src; int O, co;
    if (ch == 0)      { src = x1; O = 64;  co = cl; }
    else if (ch == 1) { src = x2; O = 64;  co = cl; }
    else if (ch < 4)  { src = x3; O = 128; co = (ch - 2) * 64 + cl; }
    else              { src = x4; O = 256; co = (ch - 4) * 64 + cl; }
    float mx = -3e38f, s = 0.f;
    for (int n = ng; n < Nn; n += 4) {
        float v = src[((size_t)b * Nn + n) * O + co];
        mx = fmaxf(mx, v);
        s += v;
    }
    __shared__ float smx[256], ssm[256];
    smx[threadIdx.x] = mx; ssm[threadIdx.x] = s;
    __syncthreads();
    if (ng == 0) {
#pragma unroll
        for (int g = 1; g < 4; ++g) { mx = fmaxf(mx, smx[g * 64 + cl]); s += ssm[g * 64 + cl]; }
        int c = ch * 64 + cl;
        gv[b * 1024 + c] = mx;
        gv[b * 1024 + 512 + c] = s * (1.f / (float)Nn);
    }
}

// ------------------------------------------------------------------- MLP head

__global__ void head_kernel(const float* __restrict__ gv,
                            const float* __restrict__ fct1, const float* __restrict__ fc1b,
                            const float* __restrict__ ln1g, const float* __restrict__ ln1b,
                            const float* __restrict__ fct2, const float* __restrict__ fc2b,
                            const float* __restrict__ ln2g, const float* __restrict__ ln2b,
                            float* __restrict__ out) {
    const int b = blockIdx.x;
    const int tid = threadIdx.x;
    __shared__ float gx[1024];
    __shared__ float hh[512];
    __shared__ float red[256];
    for (int e = tid; e < 1024; e += 256) gx[e] = gv[b * 1024 + e];
    __syncthreads();
    float h0 = fc1b[tid], h1 = fc1b[tid + 256];
    for (int c = 0; c < 1024; ++c) {
        float gc = gx[c];
        h0 = fmaf(gc, fct1[(size_t)c * 512 + tid], h0);
        h1 = fmaf(gc, fct1[(size_t)c * 512 + tid + 256], h1);
    }
    // LayerNorm over 512
    red[tid] = h0 + h1;
    __syncthreads();
    for (int st = 128; st > 0; st >>= 1) { if (tid < st) red[tid] += red[tid + st]; __syncthreads(); }
    float mu = red[0] * (1.f / 512.f);
    __syncthreads();
    float d0 = h0 - mu, d1 = h1 - mu;
    red[tid] = d0 * d0 + d1 * d1;
    __syncthreads();
    for (int st = 128; st > 0; st >>= 1) { if (tid < st) red[tid] += red[tid + st]; __syncthreads(); }
    float rs = 1.f / sqrtf(red[0] * (1.f / 512.f) + EPSV);
    __syncthreads();
    hh[tid]       = fmaxf(d0 * rs * ln1g[tid] + ln1b[tid], 0.f);
    hh[tid + 256] = fmaxf(d1 * rs * ln1g[tid + 256] + ln1b[tid + 256], 0.f);
    __syncthreads();
    float z = fc2b[tid];
    for (int c = 0; c < 512; ++c) z = fmaf(hh[c], fct2[(size_t)c * 256 + tid], z);
    red[tid] = z;
    __syncthreads();
    for (int st = 128; st > 0; st >>= 1) { if (tid < st) red[tid] += red[tid + st]; __syncthreads(); }
    float mu2 = red[0] * (1.f / 256.f);
    __syncthreads();
    float dz = z - mu2;
    red[tid] = dz * dz;
    __syncthreads();
    for (int st = 128; st > 0; st >>= 1) { if (tid < st) red[tid] += red[tid + st]; __syncthreads(); }
    float rs2 = 1.f / sqrtf(red[0] * (1.f / 256.f) + EPSV);
    out[b * 256 + tid] = dz * rs2 * ln2g[tid] + ln2b[tid];
}

// --------------------------------------------------------------- layer driver

template<int C, int O>
static void run_layer(const float* x, const float* W, const float* gamma, const float* beta,
                      float* xout, float* DIST, float* XX, int* IDX, float* Z1, float* Z2,
                      float* VMX, float* VMN, float* SSUM, float* SSQ, float* BNS, float* BNB,
                      float* WT, bool big, hipStream_t stream) {
    sqnorm_kernel<<<Bb * Nn / 256, 256, 0, stream>>>(x, XX, C);
    transpose_kernel<<<(O * 2 * C + 255) / 256, 256, 0, stream>>>(W, WT, O, 2 * C);
    z_kernel<C, O><<<Bb * Nn / 16, 256, 0, stream>>>(x, WT, Z1, Z2);
    zero_kernel<<<(2 * 64 * 256) / 256, 256, 0, stream>>>(SSUM, 2 * 64 * 256); // SSUM+SSQ contiguous
    if (big) {
        gram_dist_kernel<C><<<dim3(Nn / 64, Nn / 64, Bb), 256, 0, stream>>>(x, XX, DIST, 0, (size_t)Nn * Nn);
        topk_kernel<<<Bb * Nn, 256, 0, stream>>>(DIST, IDX, 0, (size_t)Nn * Nn);
    } else {
        for (int b = 0; b < Bb; ++b) {
            gram_dist_kernel<C><<<dim3(Nn / 64, Nn / 64, 1), 256, 0, stream>>>(x, XX, DIST, b, 0);
            topk_kernel<<<Nn, 256, 0, stream>>>(DIST, IDX, b, 0);
        }
    }
    edge_stats_kernel<O><<<Bb * Nn, 256, 0, stream>>>(Z1, Z2, IDX, VMX, VMN, SSUM, SSQ);
    bn_finalize_kernel<<<1, 256, 0, stream>>>(SSUM, SSQ, gamma, beta, BNS, BNB, O);
    apply_kernel<<<(Bb * Nn * O) / 256, 256, 0, stream>>>(VMX, VMN, BNS, BNB, xout, O, Bb * Nn * O);
}

extern "C" void kernel_launch(void* const* d_in, const int* in_sizes, int n_in,
                              void* d_out, int out_size, void* d_ws, size_t ws_size,
                              hipStream_t stream) {
    const float* points = (const float*)d_in[0];
    const float* W1 = (const float*)d_in[1];
    const float* g1 = (const float*)d_in[2];
    const float* b1 = (const float*)d_in[3];
    const float* W2 = (const float*)d_in[4];
    const float* g2 = (const float*)d_in[5];
    const float* b2 = (const float*)d_in[6];
    const float* W3 = (const float*)d_in[7];
    const float* g3 = (const float*)d_in[8];
    const float* b3 = (const float*)d_in[9];
    const float* W4 = (const float*)d_in[10];
    const float* g4 = (const float*)d_in[11];
    const float* b4 = (const float*)d_in[12];
    const float* fc1_w = (const float*)d_in[13];
    const float* fc1_b = (const float*)d_in[14];
    const float* ln1g = (const float*)d_in[15];
    const float* ln1b = (const float*)d_in[16];
    const float* fc2_w = (const float*)d_in[17];
    const float* fc2_b = (const float*)d_in[18];
    const float* ln2g = (const float*)d_in[19];
    const float* ln2b = (const float*)d_in[20];
    // d_in[21] = k (always 20 for this problem)

    float* ws = (float*)d_ws;
    const size_t BN = (size_t)Bb * Nn;
    const bool big = ws_size >= (size_t)59826688 * 4;   // full-batch dist buffer fits?

    size_t off = 0;
    auto take = [&](size_t n) { size_t o = off; off += n; return o; };
    float* DIST = ws + take(big ? (size_t)Bb * Nn * Nn : (size_t)Nn * Nn);
    float* XX   = ws + take(BN);
    int*   IDX  = (int*)(ws + take(BN * Kn));
    float* Z1   = ws + take(BN * 256);
    float* Z2   = ws + take(BN * 256);
    float* VMX  = ws + take(BN * 256);
    float* VMN  = ws + take(BN * 256);
    float* SSUM = ws + take(64 * 256);
    float* SSQ  = ws + take(64 * 256);
    float* BNS  = ws + take(256);
    float* BNB  = ws + take(256);
    float* WT   = ws + take(65536);
    float* FCT1 = ws + take(524288);
    float* FCT2 = ws + take(131072);
    float* X1   = ws + take(BN * 64);
    float* X2   = ws + take(BN * 64);
    float* X3   = ws + take(BN * 128);
    float* X4   = ws + take(BN * 256);
    float* GV   = ws + take((size_t)Bb * 1024);

    run_layer<3, 64>(points, W1, g1, b1, X1, DIST, XX, IDX, Z1, Z2, VMX, VMN, SSUM, SSQ, BNS, BNB, WT, big, stream);
    run_layer<64, 64>(X1, W2, g2, b2, X2, DIST, XX, IDX, Z1, Z2, VMX, VMN, SSUM, SSQ, BNS, BNB, WT, big, stream);
    run_layer<64, 128>(X2, W3, g3, b3, X3, DIST, XX, IDX, Z1, Z2, VMX, VMN, SSUM, SSQ, BNS, BNB, WT, big, stream);
    run_layer<128, 256>(X3, W4, g4, b4, X4, DIST, XX, IDX, Z1, Z2, VMX, VMN, SSUM, SSQ, BNS, BNB, WT, big, stream);

    pool_kernel<<<64, 256, 0, stream>>>(X1, X2, X3, X4, GV);
    transpose_kernel<<<(512 * 1024 + 255) / 256, 256, 0, stream>>>(fc1_w, FCT1, 512, 1024);
    transpose_kernel<<<(256 * 512 + 255) / 256, 256, 0, stream>>>(fc2_w, FCT2, 256, 512);
    head_kernel<<<Bb, 256, 0, stream>>>(GV, FCT1, fc1_b, ln1g, ln1b, FCT2, fc2_b, ln2g, ln2b,
                                        (float*)d_out);
}

// Round 2
// 1222.993 us; speedup vs baseline: 1.7953x; 1.7953x over previous
//
#include <hip/hip_runtime.h>
#include <cstdint>
#include <cstddef>

static constexpr int Bb = 8;
static constexpr int Nn = 2048;
static constexpr int Kn = 20;
static constexpr float EPSV = 1e-5f;

// ---------------------------------------------------------------- utilities

__global__ void zero_kernel(float* __restrict__ p, int n) {
    int i = blockIdx.x * 256 + threadIdx.x;
    if (i < n) p[i] = 0.f;
}

__global__ void sqnorm_kernel(const float* __restrict__ x, float* __restrict__ xx, int C) {
    int i = blockIdx.x * 256 + threadIdx.x;   // grid sized exactly B*N
    const float* xr = x + (size_t)i * C;
    float s = 0.f;
    for (int c = 0; c < C; ++c) { float v = xr[c]; s += v * v; }
    xx[i] = s;
}

// out[c*R + r] = in[r*Cc + c]   (small matrices, once per launch)
__global__ void transpose_kernel(const float* __restrict__ in, float* __restrict__ out,
                                 int R, int Cc) {
    int i = blockIdx.x * 256 + threadIdx.x;
    if (i < R * Cc) {
        int r = i / Cc, c = i % Cc;
        out[(size_t)c * R + r] = in[i];
    }
}

// ------------------------------------------------ pairwise sq-dist (tiled gram)

template<int C>
__global__ void gram_dist_kernel(const float* __restrict__ x, const float* __restrict__ xx,
                                 float* __restrict__ dist, int b0, size_t dstride) {
    const int b = b0 + blockIdx.z;
    const int i0 = blockIdx.y * 64, j0 = blockIdx.x * 64;
    const int tid = threadIdx.x;
    const int tx = tid & 15, ty = tid >> 4;
    __shared__ float As[64][17], Bs[64][17];
    float acc[4][4] = {};
    const float* xb = x + (size_t)b * Nn * C;
    for (int c0 = 0; c0 < C; c0 += 16) {
#pragma unroll
        for (int q = 0; q < 4; ++q) {
            int e = tid + q * 256;
            int r = e >> 4, c = e & 15;
            float av = 0.f, bv = 0.f;
            if (c0 + c < C) {
                av = xb[(size_t)(i0 + r) * C + (c0 + c)];
                bv = xb[(size_t)(j0 + r) * C + (c0 + c)];
            }
            As[r][c] = av;
            Bs[r][c] = bv;
        }
        __syncthreads();
#pragma unroll
        for (int cc = 0; cc < 16; ++cc) {
            float av[4], bv[4];
#pragma unroll
            for (int u = 0; u < 4; ++u) av[u] = As[ty * 4 + u][cc];
#pragma unroll
            for (int v = 0; v < 4; ++v) bv[v] = Bs[tx * 4 + v][cc];
#pragma unroll
            for (int u = 0; u < 4; ++u)
#pragma unroll
                for (int v = 0; v < 4; ++v)
                    acc[u][v] = fmaf(av[u], bv[v], acc[u][v]);
        }
        __syncthreads();
    }
    const float* xxb = xx + (size_t)b * Nn;
    float xi[4], xj[4];
#pragma unroll
    for (int u = 0; u < 4; ++u) xi[u] = xxb[i0 + ty * 4 + u];
#pragma unroll
    for (int v = 0; v < 4; ++v) xj[v] = xxb[j0 + tx * 4 + v];
    float* db = dist + (size_t)blockIdx.z * dstride;
#pragma unroll
    for (int u = 0; u < 4; ++u)
#pragma unroll
        for (int v = 0; v < 4; ++v)
            db[(size_t)(i0 + ty * 4 + u) * Nn + (j0 + tx * 4 + v)] =
                xi[u] + xj[v] - 2.f * acc[u][v];
}

// ------------------------------------------------------- top-k (k=20 smallest)
// One wave (64 lanes) per row; no __syncthreads. Per-lane static sorted top-4
// with rare mask-based refill; 20 rounds of (val,idx)-lexicographic butterfly.

__device__ __forceinline__ bool lex_less(float v1, int j1, float v2, int j2) {
    return v1 < v2 || (v1 == v2 && j1 < j2);
}

__device__ __forceinline__ void top4_build(const float4* __restrict__ dr4, int lane,
                                           unsigned xmask,
                                           float& tv0, int& tj0, int& ts0,
                                           float& tv1, int& tj1, int& ts1,
                                           float& tv2, int& tj2, int& ts2,
                                           float& tv3, int& tj3, int& ts3) {
    tv0 = tv1 = tv2 = tv3 = 3e38f;
    tj0 = tj1 = tj2 = tj3 = 1 << 30;
    ts0 = ts1 = ts2 = ts3 = 0;
#pragma unroll
    for (int q = 0; q < 8; ++q) {
        float4 f = dr4[q * 64 + lane];
        float vv[4] = {f.x, f.y, f.z, f.w};
#pragma unroll
        for (int c = 0; c < 4; ++c) {
            int s = q * 4 + c;
            if ((xmask >> s) & 1u) continue;
            int j = (q * 64 + lane) * 4 + c;
            float v = vv[c];
            if (lex_less(v, j, tv3, tj3)) {
                tv3 = v; tj3 = j; ts3 = s;
                if (lex_less(tv3, tj3, tv2, tj2)) {
                    float fv = tv2; int fj = tj2, fs = ts2;
                    tv2 = tv3; tj2 = tj3; ts2 = ts3; tv3 = fv; tj3 = fj; ts3 = fs;
                }
                if (lex_less(tv2, tj2, tv1, tj1)) {
                    float fv = tv1; int fj = tj1, fs = ts1;
                    tv1 = tv2; tj1 = tj2; ts1 = ts2; tv2 = fv; tj2 = fj; ts2 = fs;
                }
                if (lex_less(tv1, tj1, tv0, tj0)) {
                    float fv = tv0; int fj = tj0, fs = ts0;
                    tv0 = tv1; tj0 = tj1; ts0 = ts1; tv1 = fv; tj1 = fj; ts1 = fs;
                }
            }
        }
    }
}

__global__ void topk_kernel(const float* __restrict__ dist, int* __restrict__ idxo,
                            int b0, size_t dstride, int rows_per_batch_only) {
    const int w = threadIdx.x >> 6;               // wave within block (4 waves)
    const int lane = threadIdx.x & 63;
    const int lin = blockIdx.x * 4 + w;           // row id
    int bz, i;
    if (rows_per_batch_only) { bz = 0; i = lin; }
    else { bz = lin >> 11; i = lin & (Nn - 1); }
    const int b = b0 + bz;
    const float4* dr4 = (const float4*)(dist + (size_t)bz * dstride + (size_t)i * Nn);

    float tv0, tv1, tv2, tv3;
    int tj0, tj1, tj2, tj3, ts0, ts1, ts2, ts3;
    unsigned xmask = 0;
    top4_build(dr4, lane, 0u, tv0, tj0, ts0, tv1, tj1, ts1, tv2, tj2, ts2, tv3, tj3, ts3);
    int cnt = 0;

    int* orow = idxo + ((size_t)b * Nn + i) * Kn;
    for (int t = 0; t < Kn; ++t) {
        float bv = tv0; int bj = tj0;
#pragma unroll
        for (int off = 1; off < 64; off <<= 1) {
            float ov = __shfl_xor(bv, off);
            int oj = __shfl_xor(bj, off);
            if (lex_less(ov, oj, bv, bj)) { bv = ov; bj = oj; }
        }
        if (lane == 0) orow[t] = bj;
        if (tj0 == bj) {                           // this lane owned the winner
            xmask |= 1u << ts0;
            tv0 = tv1; tj0 = tj1; ts0 = ts1;
            tv1 = tv2; tj1 = tj2; ts1 = ts2;
            tv2 = tv3; tj2 = tj3; ts2 = ts3;
            tv3 = 3e38f; tj3 = 1 << 30; ts3 = 0;
            if (++cnt == 4) {                      // rare: lane exhausted its top-4
                top4_build(dr4, lane, xmask, tv0, tj0, ts0, tv1, tj1, ts1,
                           tv2, tj2, ts2, tv3, tj3, ts3);
                cnt = 0;
            }
        }
    }
}

// ------------------------------------- per-point projections Z1=X Wl^T, Z2=X Wr^T

template<int C, int O>
__global__ void z_kernel(const float* __restrict__ x, const float* __restrict__ wt,
                         float* __restrict__ z1, float* __restrict__ z2) {
    constexpr int TP = 16;
    constexpr int G = 256 / O;
    constexpr int PP = TP / G;
    const int p0 = blockIdx.x * TP;
    const int tid = threadIdx.x;
    const int oo = tid % O;
    const int g = tid / O;
    __shared__ float xs[TP][(C < 4) ? 4 : C];
    for (int e = tid; e < TP * C; e += 256) {
        int p = e / C, c = e % C;
        xs[p][c] = x[(size_t)(p0 + p) * C + c];
    }
    __syncthreads();
    float a1[PP], a2[PP];
#pragma unroll
    for (int p = 0; p < PP; ++p) { a1[p] = 0.f; a2[p] = 0.f; }
    if constexpr (C % 4 == 0) {
        for (int c = 0; c < C; c += 4) {
            float w1[4], w2[4];
#pragma unroll
            for (int q = 0; q < 4; ++q) {
                w1[q] = wt[(size_t)(c + q) * O + oo];
                w2[q] = wt[(size_t)(C + c + q) * O + oo];
            }
#pragma unroll
            for (int p = 0; p < PP; ++p) {
                const float4 xv = *(const float4*)(&xs[g * PP + p][c]);
                a1[p] = fmaf(xv.w, w1[3], fmaf(xv.z, w1[2], fmaf(xv.y, w1[1], fmaf(xv.x, w1[0], a1[p]))));
                a2[p] = fmaf(xv.w, w2[3], fmaf(xv.z, w2[2], fmaf(xv.y, w2[1], fmaf(xv.x, w2[0], a2[p]))));
            }
        }
    } else {
        for (int c = 0; c < C; ++c) {
            float w1 = wt[(size_t)c * O + oo];
            float w2 = wt[(size_t)(C + c) * O + oo];
#pragma unroll
            for (int p = 0; p < PP; ++p) {
                float xv = xs[g * PP + p][c];
                a1[p] = fmaf(xv, w1, a1[p]);
                a2[p] = fmaf(xv, w2, a2[p]);
            }
        }
    }
#pragma unroll
    for (int p = 0; p < PP; ++p) {
        size_t row = (size_t)(p0 + g * PP + p) * O + oo;
        z1[row] = a1[p];
        z2[row] = a2[p];
    }
}

// -------------------- gather edges, max/min over k + BN partial sums (per channel)

template<int O>
__global__ void edge_stats_kernel(const float* __restrict__ z1, const float* __restrict__ z2,
                                  const int* __restrict__ idx,
                                  float* __restrict__ vmax, float* __restrict__ vmin,
                                  float* __restrict__ ssum, float* __restrict__ ssq) {
    constexpr int G = 256 / O;
    constexpr int KK = Kn / G;          // 20 / {1,2,4}
    const int bi = blockIdx.x;          // 0 .. B*N-1
    const int b = bi >> 11;
    const int tid = threadIdx.x;
    const int oo = tid % O;
    const int g = tid / O;
    __shared__ int jl[Kn];
    if (tid < Kn) jl[tid] = idx[(size_t)bi * Kn + tid];
    __syncthreads();
    const float zi1 = z1[(size_t)bi * O + oo];
    const float a = z2[(size_t)bi * O + oo] - zi1;
    float mx = -3e38f, mn = 3e38f, s = 0.f, s2 = 0.f;
    for (int kk = 0; kk < KK; ++kk) {
        int j = jl[g * KK + kk];
        float v = z1[((size_t)b * Nn + j) * O + oo] + a;
        mx = fmaxf(mx, v);
        mn = fminf(mn, v);
        s += v;
        s2 = fmaf(v, v, s2);
    }
    if constexpr (G > 1) {
        __shared__ float smx[256], smn[256], ssm[256], sqq[256];
        smx[tid] = mx; smn[tid] = mn; ssm[tid] = s; sqq[tid] = s2;
        __syncthreads();
        if (tid < O) {
#pragma unroll
            for (int gg = 1; gg < G; ++gg) {
                mx = fmaxf(mx, smx[gg * O + oo]);
                mn = fminf(mn, smn[gg * O + oo]);
                s += ssm[gg * O + oo];
                s2 += sqq[gg * O + oo];
            }
        }
    }
    if (tid < O) {
        vmax[(size_t)bi * O + oo] = mx;
        vmin[(size_t)bi * O + oo] = mn;
        int slot = bi & 63;
        atomicAdd(&ssum[slot * O + oo], s);
        atomicAdd(&ssq[slot * O + oo], s2);
    }
}

__global__ void bn_finalize_kernel(const float* __restrict__ ssum, const float* __restrict__ ssq,
                                   const float* __restrict__ gamma, const float* __restrict__ beta,
                                   float* __restrict__ scale, float* __restrict__ shift, int O) {
    int o = threadIdx.x;
    if (o >= O) return;
    float s = 0.f, q = 0.f;
    for (int sl = 0; sl < 64; ++sl) { s += ssum[sl * O + o]; q += ssq[sl * O + o]; }
    const float cnt = (float)Bb * (float)Nn * (float)Kn;
    float mu = s / cnt;
    float var = q / cnt - mu * mu;
    float sc = gamma[o] / sqrtf(var + EPSV);
    scale[o] = sc;
    shift[o] = beta[o] - mu * sc;
}

__global__ void apply_kernel(const float* __restrict__ vmax, const float* __restrict__ vmin,
                             const float* __restrict__ scale, const float* __restrict__ shift,
                             float* __restrict__ xout, int O, int total) {
    int i = blockIdx.x * 256 + threadIdx.x;
    if (i >= total) return;
    int o = i % O;
    float sc = scale[o];
    float v = (sc >= 0.f) ? vmax[i] : vmin[i];   // max/min commute with monotone affine
    xout[i] = fmaxf(fmaf(v, sc, shift[o]), 0.f);
}

// ------------------------------------------------------- global max+mean pool

__global__ void pool_kernel(const float* __restrict__ x1, const float* __restrict__ x2,
                            const float* __restrict__ x3, const float* __restrict__ x4,
                            float* __restrict__ gv) {
    int blk = blockIdx.x;           // 64 blocks: b(8) x chunk(8)
    int b = blk >> 3, ch = blk & 7;
    int cl = threadIdx.x & 63, ng = threadIdx.x >> 6;
    const float* src; int O, co;
    if (ch == 0)      { src = x1; O = 64;  co = cl; }
    else if (ch == 1) { src = x2; O = 64;  co = cl; }
    else if (ch < 4)  { src = x3; O = 128; co = (ch - 2) * 64 + cl; }
    else              { src = x4; O = 256; co = (ch - 4) * 64 + cl; }
    float mx = -3e38f, s = 0.f;
    for (int n = ng; n < Nn; n += 4) {
        float v = src[((size_t)b * Nn + n) * O + co];
        mx = fmaxf(mx, v);
        s += v;
    }
    __shared__ float smx[256], ssm[256];
    smx[threadIdx.x] = mx; ssm[threadIdx.x] = s;
    __syncthreads();
    if (ng == 0) {
#pragma unroll
        for (int g = 1; g < 4; ++g) { mx = fmaxf(mx, smx[g * 64 + cl]); s += ssm[g * 64 + cl]; }
        int c = ch * 64 + cl;
        gv[b * 1024 + c] = mx;
        gv[b * 1024 + 512 + c] = s * (1.f / (float)Nn);
    }
}

// ------------------------------------------------------------------- MLP head

__global__ void head_kernel(const float* __restrict__ gv,
                            const float* __restrict__ fct1, const float* __restrict__ fc1b,
                            const float* __restrict__ ln1g, const float* __restrict__ ln1b,
                            const float* __restrict__ fct2, const float* __restrict__ fc2b,
                            const float* __restrict__ ln2g, const float* __restrict__ ln2b,
                            float* __restrict__ out) {
    const int b = blockIdx.x;
    const int tid = threadIdx.x;
    __shared__ float gx[1024];
    __shared__ float hh[512];
    __shared__ float red[256];
    for (int e = tid; e < 1024; e += 256) gx[e] = gv[b * 1024 + e];
    __syncthreads();
    float h0 = fc1b[tid], h1 = fc1b[tid + 256];
    for (int c = 0; c < 1024; ++c) {
        float gc = gx[c];
        h0 = fmaf(gc, fct1[(size_t)c * 512 + tid], h0);
        h1 = fmaf(gc, fct1[(size_t)c * 512 + tid + 256], h1);
    }
    // LayerNorm over 512
    red[tid] = h0 + h1;
    __syncthreads();
    for (int st = 128; st > 0; st >>= 1) { if (tid < st) red[tid] += red[tid + st]; __syncthreads(); }
    float mu = red[0] * (1.f / 512.f);
    __syncthreads();
    float d0 = h0 - mu, d1 = h1 - mu;
    red[tid] = d0 * d0 + d1 * d1;
    __syncthreads();
    for (int st = 128; st > 0; st >>= 1) { if (tid < st) red[tid] += red[tid + st]; __syncthreads(); }
    float rs = 1.f / sqrtf(red[0] * (1.f / 512.f) + EPSV);
    __syncthreads();
    hh[tid]       = fmaxf(d0 * rs * ln1g[tid] + ln1b[tid], 0.f);
    hh[tid + 256] = fmaxf(d1 * rs * ln1g[tid + 256] + ln1b[tid + 256], 0.f);
    __syncthreads();
    float z = fc2b[tid];
    for (int c = 0; c < 512; ++c) z = fmaf(hh[c], fct2[(size_t)c * 256 + tid], z);
    red[tid] = z;
    __syncthreads();
    for (int st = 128; st > 0; st >>= 1) { if (tid < st) red[tid] += red[tid + st]; __syncthreads(); }
    float mu2 = red[0] * (1.f / 256.f);
    __syncthreads();
    float dz = z - mu2;
    red[tid] = dz * dz;
    __syncthreads();
    for (int st = 128; st > 0; st >>= 1) { if (tid < st) red[tid] += red[tid + st]; __syncthreads(); }
    float rs2 = 1.f / sqrtf(red[0] * (1.f / 256.f) + EPSV);
    out[b * 256 + tid] = dz * rs2 * ln2g[tid] + ln2b[tid];
}

// --------------------------------------------------------------- layer driver

template<int C, int O>
static void run_layer(const float* x, const float* W, const float* gamma, const float* beta,
                      float* xout, float* DIST, float* XX, int* IDX, float* Z1, float* Z2,
                      float* VMX, float* VMN, float* SSUM, float* SSQ, float* BNS, float* BNB,
                      float* WT, bool big, hipStream_t stream) {
    sqnorm_kernel<<<Bb * Nn / 256, 256, 0, stream>>>(x, XX, C);
    transpose_kernel<<<(O * 2 * C + 255) / 256, 256, 0, stream>>>(W, WT, O, 2 * C);
    z_kernel<C, O><<<Bb * Nn / 16, 256, 0, stream>>>(x, WT, Z1, Z2);
    zero_kernel<<<(2 * 64 * 256) / 256, 256, 0, stream>>>(SSUM, 2 * 64 * 256); // SSUM+SSQ contiguous
    if (big) {
        gram_dist_kernel<C><<<dim3(Nn / 64, Nn / 64, Bb), 256, 0, stream>>>(x, XX, DIST, 0, (size_t)Nn * Nn);
        topk_kernel<<<Bb * Nn / 4, 256, 0, stream>>>(DIST, IDX, 0, (size_t)Nn * Nn, 0);
    } else {
        for (int b = 0; b < Bb; ++b) {
            gram_dist_kernel<C><<<dim3(Nn / 64, Nn / 64, 1), 256, 0, stream>>>(x, XX, DIST, b, 0);
            topk_kernel<<<Nn / 4, 256, 0, stream>>>(DIST, IDX, b, 0, 1);
        }
    }
    edge_stats_kernel<O><<<Bb * Nn, 256, 0, stream>>>(Z1, Z2, IDX, VMX, VMN, SSUM, SSQ);
    bn_finalize_kernel<<<1, 256, 0, stream>>>(SSUM, SSQ, gamma, beta, BNS, BNB, O);
    apply_kernel<<<(Bb * Nn * O) / 256, 256, 0, stream>>>(VMX, VMN, BNS, BNB, xout, O, Bb * Nn * O);
}

extern "C" void kernel_launch(void* const* d_in, const int* in_sizes, int n_in,
                              void* d_out, int out_size, void* d_ws, size_t ws_size,
                              hipStream_t stream) {
    const float* points = (const float*)d_in[0];
    const float* W1 = (const float*)d_in[1];
    const float* g1 = (const float*)d_in[2];
    const float* b1 = (const float*)d_in[3];
    const float* W2 = (const float*)d_in[4];
    const float* g2 = (const float*)d_in[5];
    const float* b2 = (const float*)d_in[6];
    const float* W3 = (const float*)d_in[7];
    const float* g3 = (const float*)d_in[8];
    const float* b3 = (const float*)d_in[9];
    const float* W4 = (const float*)d_in[10];
    const float* g4 = (const float*)d_in[11];
    const float* b4 = (const float*)d_in[12];
    const float* fc1_w = (const float*)d_in[13];
    const float* fc1_b = (const float*)d_in[14];
    const float* ln1g = (const float*)d_in[15];
    const float* ln1b = (const float*)d_in[16];
    const float* fc2_w = (const float*)d_in[17];
    const float* fc2_b = (const float*)d_in[18];
    const float* ln2g = (const float*)d_in[19];
    const float* ln2b = (const float*)d_in[20];
    // d_in[21] = k (always 20 for this problem)

    float* ws = (float*)d_ws;
    const size_t BN = (size_t)Bb * Nn;
    const bool big = ws_size >= (size_t)59826688 * 4;   // full-batch dist buffer fits?

    size_t off = 0;
    auto take = [&](size_t n) { size_t o = off; off += n; return o; };
    float* DIST = ws + take(big ? (size_t)Bb * Nn * Nn : (size_t)Nn * Nn);
    float* XX   = ws + take(BN);
    int*   IDX  = (int*)(ws + take(BN * Kn));
    float* Z1   = ws + take(BN * 256);
    float* Z2   = ws + take(BN * 256);
    float* VMX  = ws + take(BN * 256);
    float* VMN  = ws + take(BN * 256);
    float* SSUM = ws + take(64 * 256);
    float* SSQ  = ws + take(64 * 256);
    float* BNS  = ws + take(256);
    float* BNB  = ws + take(256);
    float* WT   = ws + take(65536);
    float* FCT1 = ws + take(524288);
    float* FCT2 = ws + take(131072);
    float* X1   = ws + take(BN * 64);
    float* X2   = ws + take(BN * 64);
    float* X3   = ws + take(BN * 128);
    float* X4   = ws + take(BN * 256);
    float* GV   = ws + take((size_t)Bb * 1024);

    run_layer<3, 64>(points, W1, g1, b1, X1, DIST, XX, IDX, Z1, Z2, VMX, VMN, SSUM, SSQ, BNS, BNB, WT, big, stream);
    run_layer<64, 64>(X1, W2, g2, b2, X2, DIST, XX, IDX, Z1, Z2, VMX, VMN, SSUM, SSQ, BNS, BNB, WT, big, stream);
    run_layer<64, 128>(X2, W3, g3, b3, X3, DIST, XX, IDX, Z1, Z2, VMX, VMN, SSUM, SSQ, BNS, BNB, WT, big, stream);
    run_layer<128, 256>(X3, W4, g4, b4, X4, DIST, XX, IDX, Z1, Z2, VMX, VMN, SSUM, SSQ, BNS, BNB, WT, big, stream);

    pool_kernel<<<64, 256, 0, stream>>>(X1, X2, X3, X4, GV);
    transpose_kernel<<<(512 * 1024 + 255) / 256, 256, 0, stream>>>(fc1_w, FCT1, 512, 1024);
    transpose_kernel<<<(256 * 512 + 255) / 256, 256, 0, stream>>>(fc2_w, FCT2, 256, 512);
    head_kernel<<<Bb, 256, 0, stream>>>(GV, FCT1, fc1_b, ln1g, ln1b, FCT2, fc2_b, ln2g, ln2b,
                                        (float*)d_out);
}

// Round 3
// 1103.701 us; speedup vs baseline: 1.9893x; 1.1081x over previous
//
#include <hip/hip_runtime.h>
#include <cstdint>
#include <cstddef>

static constexpr int Bb = 8;
static constexpr int Nn = 2048;
static constexpr int Kn = 20;
static constexpr float EPSV = 1e-5f;

// ---------------------------------------------------------------- utilities

__global__ void zero_kernel(float* __restrict__ p, int n) {
    int i = blockIdx.x * 256 + threadIdx.x;
    if (i < n) p[i] = 0.f;
}

__global__ void sqnorm_kernel(const float* __restrict__ x, float* __restrict__ xx, int C) {
    int i = blockIdx.x * 256 + threadIdx.x;   // grid sized exactly B*N
    const float* xr = x + (size_t)i * C;
    float s = 0.f;
    for (int c = 0; c < C; ++c) { float v = xr[c]; s += v * v; }
    xx[i] = s;
}

// out[c*R + r] = in[r*Cc + c]   (small matrices, once per launch)
__global__ void transpose_kernel(const float* __restrict__ in, float* __restrict__ out,
                                 int R, int Cc) {
    int i = blockIdx.x * 256 + threadIdx.x;
    if (i < R * Cc) {
        int r = i / Cc, c = i % Cc;
        out[(size_t)c * R + r] = in[i];
    }
}

// ------------------------------------------------ pairwise sq-dist (tiled gram)
// 128x128 tile per block, 8x8 per thread, transposed LDS (As[cc][i]) so
// fragments load as ds_read_b128. B is split into BsA/BsB (stride 68) so the
// 16 tx-groups alias banks 2-way (free) instead of 4-way.

template<int C>
__global__ __launch_bounds__(256, 2)
void gram_dist_kernel(const float* __restrict__ x, const float* __restrict__ xx,
                      float* __restrict__ dist, int b0, size_t dstride) {
    constexpr int CT = (C < 16) ? C : 16;
    const int b = b0 + blockIdx.z;
    const int i0 = blockIdx.y * 128, j0 = blockIdx.x * 128;
    const int tid = threadIdx.x;
    const int tx = tid & 15, ty = tid >> 4;
    __shared__ float As[CT][136];
    __shared__ float BsA[CT][68];
    __shared__ float BsB[CT][68];
    float acc[8][8] = {};
    const float* xb = x + (size_t)b * Nn * C;

    const int si = tid & 127;         // staging row
    const int half = tid >> 7;        // 0..1
    // B-side scatter target for row si: element (c, si) -> bbase[c*68]
    float* bbase = ((si & 4) ? &BsB[0][0] : &BsA[0][0]) + (((si >> 3) << 2) | (si & 3));

    for (int c0 = 0; c0 < C; c0 += CT) {
        if constexpr (CT == 16) {
            const float* ra = xb + (size_t)(i0 + si) * C + c0 + half * 8;
            const float* rb = xb + (size_t)(j0 + si) * C + c0 + half * 8;
            float4 a0 = *(const float4*)ra;
            float4 a1 = *(const float4*)(ra + 4);
            float4 bq0 = *(const float4*)rb;
            float4 bq1 = *(const float4*)(rb + 4);
            const int cb = half * 8;
            As[cb + 0][si] = a0.x; As[cb + 1][si] = a0.y;
            As[cb + 2][si] = a0.z; As[cb + 3][si] = a0.w;
            As[cb + 4][si] = a1.x; As[cb + 5][si] = a1.y;
            As[cb + 6][si] = a1.z; As[cb + 7][si] = a1.w;
            bbase[(cb + 0) * 68] = bq0.x; bbase[(cb + 1) * 68] = bq0.y;
            bbase[(cb + 2) * 68] = bq0.z; bbase[(cb + 3) * 68] = bq0.w;
            bbase[(cb + 4) * 68] = bq1.x; bbase[(cb + 5) * 68] = bq1.y;
            bbase[(cb + 6) * 68] = bq1.z; bbase[(cb + 7) * 68] = bq1.w;
        } else {
            if (half == 0) {
                const float* ra = xb + (size_t)(i0 + si) * C + c0;
#pragma unroll
                for (int c = 0; c < CT; ++c) As[c][si] = ra[c];
            } else {
                const float* rb = xb + (size_t)(j0 + si) * C + c0;
#pragma unroll
                for (int c = 0; c < CT; ++c) bbase[c * 68] = rb[c];
            }
        }
        __syncthreads();
#pragma unroll
        for (int cc = 0; cc < CT; ++cc) {
            float a[8], bv[8];
            *(float4*)&a[0]  = *(const float4*)&As[cc][ty * 8];
            *(float4*)&a[4]  = *(const float4*)&As[cc][ty * 8 + 4];
            *(float4*)&bv[0] = *(const float4*)&BsA[cc][tx * 4];
            *(float4*)&bv[4] = *(const float4*)&BsB[cc][tx * 4];
#pragma unroll
            for (int u = 0; u < 8; ++u)
#pragma unroll
                for (int v = 0; v < 8; ++v)
                    acc[u][v] = fmaf(a[u], bv[v], acc[u][v]);
        }
        __syncthreads();
    }

    const float* xxb = xx + (size_t)b * Nn;
    float xi[8], xj[8];
#pragma unroll
    for (int u = 0; u < 8; ++u) xi[u] = xxb[i0 + ty * 8 + u];
#pragma unroll
    for (int v = 0; v < 8; ++v) xj[v] = xxb[j0 + tx * 8 + v];
    float* db = dist + (size_t)blockIdx.z * dstride;
#pragma unroll
    for (int u = 0; u < 8; ++u) {
        float* row = db + (size_t)(i0 + ty * 8 + u) * Nn + (j0 + tx * 8);
        float4 o0, o1;
        o0.x = xi[u] + xj[0] - 2.f * acc[u][0];
        o0.y = xi[u] + xj[1] - 2.f * acc[u][1];
        o0.z = xi[u] + xj[2] - 2.f * acc[u][2];
        o0.w = xi[u] + xj[3] - 2.f * acc[u][3];
        o1.x = xi[u] + xj[4] - 2.f * acc[u][4];
        o1.y = xi[u] + xj[5] - 2.f * acc[u][5];
        o1.z = xi[u] + xj[6] - 2.f * acc[u][6];
        o1.w = xi[u] + xj[7] - 2.f * acc[u][7];
        *(float4*)row = o0;
        *(float4*)(row + 4) = o1;
    }
}

// ------------------------------------------------------- top-k (k=20 smallest)
// One wave (64 lanes) per row; no __syncthreads. Per-lane static sorted top-4
// with rare mask-based refill; 20 rounds of (val,idx)-lexicographic butterfly.

__device__ __forceinline__ bool lex_less(float v1, int j1, float v2, int j2) {
    return v1 < v2 || (v1 == v2 && j1 < j2);
}

__device__ __forceinline__ void top4_build(const float4* __restrict__ dr4, int lane,
                                           unsigned xmask,
                                           float& tv0, int& tj0, int& ts0,
                                           float& tv1, int& tj1, int& ts1,
                                           float& tv2, int& tj2, int& ts2,
                                           float& tv3, int& tj3, int& ts3) {
    tv0 = tv1 = tv2 = tv3 = 3e38f;
    tj0 = tj1 = tj2 = tj3 = 1 << 30;
    ts0 = ts1 = ts2 = ts3 = 0;
#pragma unroll
    for (int q = 0; q < 8; ++q) {
        float4 f = dr4[q * 64 + lane];
        float vv[4] = {f.x, f.y, f.z, f.w};
#pragma unroll
        for (int c = 0; c < 4; ++c) {
            int s = q * 4 + c;
            if ((xmask >> s) & 1u) continue;
            int j = (q * 64 + lane) * 4 + c;
            float v = vv[c];
            if (lex_less(v, j, tv3, tj3)) {
                tv3 = v; tj3 = j; ts3 = s;
                if (lex_less(tv3, tj3, tv2, tj2)) {
                    float fv = tv2; int fj = tj2, fs = ts2;
                    tv2 = tv3; tj2 = tj3; ts2 = ts3; tv3 = fv; tj3 = fj; ts3 = fs;
                }
                if (lex_less(tv2, tj2, tv1, tj1)) {
                    float fv = tv1; int fj = tj1, fs = ts1;
                    tv1 = tv2; tj1 = tj2; ts1 = ts2; tv2 = fv; tj2 = fj; ts2 = fs;
                }
                if (lex_less(tv1, tj1, tv0, tj0)) {
                    float fv = tv0; int fj = tj0, fs = ts0;
                    tv0 = tv1; tj0 = tj1; ts0 = ts1; tv1 = fv; tj1 = fj; ts1 = fs;
                }
            }
        }
    }
}

__global__ void topk_kernel(const float* __restrict__ dist, int* __restrict__ idxo,
                            int b0, size_t dstride, int rows_per_batch_only) {
    const int w = threadIdx.x >> 6;               // wave within block (4 waves)
    const int lane = threadIdx.x & 63;
    const int lin = blockIdx.x * 4 + w;           // row id
    int bz, i;
    if (rows_per_batch_only) { bz = 0; i = lin; }
    else { bz = lin >> 11; i = lin & (Nn - 1); }
    const int b = b0 + bz;
    const float4* dr4 = (const float4*)(dist + (size_t)bz * dstride + (size_t)i * Nn);

    float tv0, tv1, tv2, tv3;
    int tj0, tj1, tj2, tj3, ts0, ts1, ts2, ts3;
    unsigned xmask = 0;
    top4_build(dr4, lane, 0u, tv0, tj0, ts0, tv1, tj1, ts1, tv2, tj2, ts2, tv3, tj3, ts3);
    int cnt = 0;

    int* orow = idxo + ((size_t)b * Nn + i) * Kn;
    for (int t = 0; t < Kn; ++t) {
        float bv = tv0; int bj = tj0;
#pragma unroll
        for (int off = 1; off < 64; off <<= 1) {
            float ov = __shfl_xor(bv, off);
            int oj = __shfl_xor(bj, off);
            if (lex_less(ov, oj, bv, bj)) { bv = ov; bj = oj; }
        }
        if (lane == 0) orow[t] = bj;
        if (tj0 == bj) {                           // this lane owned the winner
            xmask |= 1u << ts0;
            tv0 = tv1; tj0 = tj1; ts0 = ts1;
            tv1 = tv2; tj1 = tj2; ts1 = ts2;
            tv2 = tv3; tj2 = tj3; ts2 = ts3;
            tv3 = 3e38f; tj3 = 1 << 30; ts3 = 0;
            if (++cnt == 4) {                      // rare: lane exhausted its top-4
                top4_build(dr4, lane, xmask, tv0, tj0, ts0, tv1, tj1, ts1,
                           tv2, tj2, ts2, tv3, tj3, ts3);
                cnt = 0;
            }
        }
    }
}

// ------------------------------------- per-point projections Z1=X Wl^T, Z2=X Wr^T

template<int C, int O>
__global__ void z_kernel(const float* __restrict__ x, const float* __restrict__ wt,
                         float* __restrict__ z1, float* __restrict__ z2) {
    constexpr int TP = 16;
    constexpr int G = 256 / O;
    constexpr int PP = TP / G;
    const int p0 = blockIdx.x * TP;
    const int tid = threadIdx.x;
    const int oo = tid % O;
    const int g = tid / O;
    __shared__ float xs[TP][(C < 4) ? 4 : C];
    for (int e = tid; e < TP * C; e += 256) {
        int p = e / C, c = e % C;
        xs[p][c] = x[(size_t)(p0 + p) * C + c];
    }
    __syncthreads();
    float a1[PP], a2[PP];
#pragma unroll
    for (int p = 0; p < PP; ++p) { a1[p] = 0.f; a2[p] = 0.f; }
    if constexpr (C % 4 == 0) {
        for (int c = 0; c < C; c += 4) {
            float w1[4], w2[4];
#pragma unroll
            for (int q = 0; q < 4; ++q) {
                w1[q] = wt[(size_t)(c + q) * O + oo];
                w2[q] = wt[(size_t)(C + c + q) * O + oo];
            }
#pragma unroll
            for (int p = 0; p < PP; ++p) {
                const float4 xv = *(const float4*)(&xs[g * PP + p][c]);
                a1[p] = fmaf(xv.w, w1[3], fmaf(xv.z, w1[2], fmaf(xv.y, w1[1], fmaf(xv.x, w1[0], a1[p]))));
                a2[p] = fmaf(xv.w, w2[3], fmaf(xv.z, w2[2], fmaf(xv.y, w2[1], fmaf(xv.x, w2[0], a2[p]))));
            }
        }
    } else {
        for (int c = 0; c < C; ++c) {
            float w1 = wt[(size_t)c * O + oo];
            float w2 = wt[(size_t)(C + c) * O + oo];
#pragma unroll
            for (int p = 0; p < PP; ++p) {
                float xv = xs[g * PP + p][c];
                a1[p] = fmaf(xv, w1, a1[p]);
                a2[p] = fmaf(xv, w2, a2[p]);
            }
        }
    }
#pragma unroll
    for (int p = 0; p < PP; ++p) {
        size_t row = (size_t)(p0 + g * PP + p) * O + oo;
        z1[row] = a1[p];
        z2[row] = a2[p];
    }
}

// -------------------- gather edges, max/min over k + BN partial sums (per channel)

template<int O>
__global__ void edge_stats_kernel(const float* __restrict__ z1, const float* __restrict__ z2,
                                  const int* __restrict__ idx,
                                  float* __restrict__ vmax, float* __restrict__ vmin,
                                  float* __restrict__ ssum, float* __restrict__ ssq) {
    constexpr int G = 256 / O;
    constexpr int KK = Kn / G;          // 20 / {1,2,4}
    const int bi = blockIdx.x;          // 0 .. B*N-1
    const int b = bi >> 11;
    const int tid = threadIdx.x;
    const int oo = tid % O;
    const int g = tid / O;
    __shared__ int jl[Kn];
    if (tid < Kn) jl[tid] = idx[(size_t)bi * Kn + tid];
    __syncthreads();
    const float zi1 = z1[(size_t)bi * O + oo];
    const float a = z2[(size_t)bi * O + oo] - zi1;
    float mx = -3e38f, mn = 3e38f, s = 0.f, s2 = 0.f;
    for (int kk = 0; kk < KK; ++kk) {
        int j = jl[g * KK + kk];
        float v = z1[((size_t)b * Nn + j) * O + oo] + a;
        mx = fmaxf(mx, v);
        mn = fminf(mn, v);
        s += v;
        s2 = fmaf(v, v, s2);
    }
    if constexpr (G > 1) {
        __shared__ float smx[256], smn[256], ssm[256], sqq[256];
        smx[tid] = mx; smn[tid] = mn; ssm[tid] = s; sqq[tid] = s2;
        __syncthreads();
        if (tid < O) {
#pragma unroll
            for (int gg = 1; gg < G; ++gg) {
                mx = fmaxf(mx, smx[gg * O + oo]);
                mn = fminf(mn, smn[gg * O + oo]);
                s += ssm[gg * O + oo];
                s2 += sqq[gg * O + oo];
            }
        }
    }
    if (tid < O) {
        vmax[(size_t)bi * O + oo] = mx;
        vmin[(size_t)bi * O + oo] = mn;
        int slot = bi & 63;
        atomicAdd(&ssum[slot * O + oo], s);
        atomicAdd(&ssq[slot * O + oo], s2);
    }
}

__global__ void bn_finalize_kernel(const float* __restrict__ ssum, const float* __restrict__ ssq,
                                   const float* __restrict__ gamma, const float* __restrict__ beta,
                                   float* __restrict__ scale, float* __restrict__ shift, int O) {
    int o = threadIdx.x;
    if (o >= O) return;
    float s = 0.f, q = 0.f;
    for (int sl = 0; sl < 64; ++sl) { s += ssum[sl * O + o]; q += ssq[sl * O + o]; }
    const float cnt = (float)Bb * (float)Nn * (float)Kn;
    float mu = s / cnt;
    float var = q / cnt - mu * mu;
    float sc = gamma[o] / sqrtf(var + EPSV);
    scale[o] = sc;
    shift[o] = beta[o] - mu * sc;
}

__global__ void apply_kernel(const float* __restrict__ vmax, const float* __restrict__ vmin,
                             const float* __restrict__ scale, const float* __restrict__ shift,
                             float* __restrict__ xout, int O, int total) {
    int i = blockIdx.x * 256 + threadIdx.x;
    if (i >= total) return;
    int o = i % O;
    float sc = scale[o];
    float v = (sc >= 0.f) ? vmax[i] : vmin[i];   // max/min commute with monotone affine
    xout[i] = fmaxf(fmaf(v, sc, shift[o]), 0.f);
}

// ------------------------------------------------------- global max+mean pool

__global__ void pool_kernel(const float* __restrict__ x1, const float* __restrict__ x2,
                            const float* __restrict__ x3, const float* __restrict__ x4,
                            float* __restrict__ gv) {
    int blk = blockIdx.x;           // 64 blocks: b(8) x chunk(8)
    int b = blk >> 3, ch = blk & 7;
    int cl = threadIdx.x & 63, ng = threadIdx.x >> 6;
    const float* src; int O, co;
    if (ch == 0)      { src = x1; O = 64;  co = cl; }
    else if (ch == 1) { src = x2; O = 64;  co = cl; }
    else if (ch < 4)  { src = x3; O = 128; co = (ch - 2) * 64 + cl; }
    else              { src = x4; O = 256; co = (ch - 4) * 64 + cl; }
    float mx = -3e38f, s = 0.f;
    for (int n = ng; n < Nn; n += 4) {
        float v = src[((size_t)b * Nn + n) * O + co];
        mx = fmaxf(mx, v);
        s += v;
    }
    __shared__ float smx[256], ssm[256];
    smx[threadIdx.x] = mx; ssm[threadIdx.x] = s;
    __syncthreads();
    if (ng == 0) {
#pragma unroll
        for (int g = 1; g < 4; ++g) { mx = fmaxf(mx, smx[g * 64 + cl]); s += ssm[g * 64 + cl]; }
        int c = ch * 64 + cl;
        gv[b * 1024 + c] = mx;
        gv[b * 1024 + 512 + c] = s * (1.f / (float)Nn);
    }
}

// ------------------------------------------------------------------- MLP head

__global__ void head_kernel(const float* __restrict__ gv,
                            const float* __restrict__ fct1, const float* __restrict__ fc1b,
                            const float* __restrict__ ln1g, const float* __restrict__ ln1b,
                            const float* __restrict__ fct2, const float* __restrict__ fc2b,
                            const float* __restrict__ ln2g, const float* __restrict__ ln2b,
                            float* __restrict__ out) {
    const int b = blockIdx.x;
    const int tid = threadIdx.x;
    __shared__ float gx[1024];
    __shared__ float hh[512];
    __shared__ float red[256];
    for (int e = tid; e < 1024; e += 256) gx[e] = gv[b * 1024 + e];
    __syncthreads();
    float h0 = fc1b[tid], h1 = fc1b[tid + 256];
    for (int c = 0; c < 1024; ++c) {
        float gc = gx[c];
        h0 = fmaf(gc, fct1[(size_t)c * 512 + tid], h0);
        h1 = fmaf(gc, fct1[(size_t)c * 512 + tid + 256], h1);
    }
    // LayerNorm over 512
    red[tid] = h0 + h1;
    __syncthreads();
    for (int st = 128; st > 0; st >>= 1) { if (tid < st) red[tid] += red[tid + st]; __syncthreads(); }
    float mu = red[0] * (1.f / 512.f);
    __syncthreads();
    float d0 = h0 - mu, d1 = h1 - mu;
    red[tid] = d0 * d0 + d1 * d1;
    __syncthreads();
    for (int st = 128; st > 0; st >>= 1) { if (tid < st) red[tid] += red[tid + st]; __syncthreads(); }
    float rs = 1.f / sqrtf(red[0] * (1.f / 512.f) + EPSV);
    __syncthreads();
    hh[tid]       = fmaxf(d0 * rs * ln1g[tid] + ln1b[tid], 0.f);
    hh[tid + 256] = fmaxf(d1 * rs * ln1g[tid + 256] + ln1b[tid + 256], 0.f);
    __syncthreads();
    float z = fc2b[tid];
    for (int c = 0; c < 512; ++c) z = fmaf(hh[c], fct2[(size_t)c * 256 + tid], z);
    red[tid] = z;
    __syncthreads();
    for (int st = 128; st > 0; st >>= 1) { if (tid < st) red[tid] += red[tid + st]; __syncthreads(); }
    float mu2 = red[0] * (1.f / 256.f);
    __syncthreads();
    float dz = z - mu2;
    red[tid] = dz * dz;
    __syncthreads();
    for (int st = 128; st > 0; st >>= 1) { if (tid < st) red[tid] += red[tid + st]; __syncthreads(); }
    float rs2 = 1.f / sqrtf(red[0] * (1.f / 256.f) + EPSV);
    out[b * 256 + tid] = dz * rs2 * ln2g[tid] + ln2b[tid];
}

// --------------------------------------------------------------- layer driver

template<int C, int O>
static void run_layer(const float* x, const float* W, const float* gamma, const float* beta,
                      float* xout, float* DIST, float* XX, int* IDX, float* Z1, float* Z2,
                      float* VMX, float* VMN, float* SSUM, float* SSQ, float* BNS, float* BNB,
                      float* WT, bool big, hipStream_t stream) {
    sqnorm_kernel<<<Bb * Nn / 256, 256, 0, stream>>>(x, XX, C);
    transpose_kernel<<<(O * 2 * C + 255) / 256, 256, 0, stream>>>(W, WT, O, 2 * C);
    z_kernel<C, O><<<Bb * Nn / 16, 256, 0, stream>>>(x, WT, Z1, Z2);
    zero_kernel<<<(2 * 64 * 256) / 256, 256, 0, stream>>>(SSUM, 2 * 64 * 256); // SSUM+SSQ contiguous
    if (big) {
        gram_dist_kernel<C><<<dim3(Nn / 128, Nn / 128, Bb), 256, 0, stream>>>(x, XX, DIST, 0, (size_t)Nn * Nn);
        topk_kernel<<<Bb * Nn / 4, 256, 0, stream>>>(DIST, IDX, 0, (size_t)Nn * Nn, 0);
    } else {
        for (int b = 0; b < Bb; ++b) {
            gram_dist_kernel<C><<<dim3(Nn / 128, Nn / 128, 1), 256, 0, stream>>>(x, XX, DIST, b, 0);
            topk_kernel<<<Nn / 4, 256, 0, stream>>>(DIST, IDX, b, 0, 1);
        }
    }
    edge_stats_kernel<O><<<Bb * Nn, 256, 0, stream>>>(Z1, Z2, IDX, VMX, VMN, SSUM, SSQ);
    bn_finalize_kernel<<<1, 256, 0, stream>>>(SSUM, SSQ, gamma, beta, BNS, BNB, O);
    apply_kernel<<<(Bb * Nn * O) / 256, 256, 0, stream>>>(VMX, VMN, BNS, BNB, xout, O, Bb * Nn * O);
}

extern "C" void kernel_launch(void* const* d_in, const int* in_sizes, int n_in,
                              void* d_out, int out_size, void* d_ws, size_t ws_size,
                              hipStream_t stream) {
    const float* points = (const float*)d_in[0];
    const float* W1 = (const float*)d_in[1];
    const float* g1 = (const float*)d_in[2];
    const float* b1 = (const float*)d_in[3];
    const float* W2 = (const float*)d_in[4];
    const float* g2 = (const float*)d_in[5];
    const float* b2 = (const float*)d_in[6];
    const float* W3 = (const float*)d_in[7];
    const float* g3 = (const float*)d_in[8];
    const float* b3 = (const float*)d_in[9];
    const float* W4 = (const float*)d_in[10];
    const float* g4 = (const float*)d_in[11];
    const float* b4 = (const float*)d_in[12];
    const float* fc1_w = (const float*)d_in[13];
    const float* fc1_b = (const float*)d_in[14];
    const float* ln1g = (const float*)d_in[15];
    const float* ln1b = (const float*)d_in[16];
    const float* fc2_w = (const float*)d_in[17];
    const float* fc2_b = (const float*)d_in[18];
    const float* ln2g = (const float*)d_in[19];
    const float* ln2b = (const float*)d_in[20];
    // d_in[21] = k (always 20 for this problem)

    float* ws = (float*)d_ws;
    const size_t BN = (size_t)Bb * Nn;
    const bool big = ws_size >= (size_t)59826688 * 4;   // full-batch dist buffer fits?

    size_t off = 0;
    auto take = [&](size_t n) { size_t o = off; off += n; return o; };
    float* DIST = ws + take(big ? (size_t)Bb * Nn * Nn : (size_t)Nn * Nn);
    float* XX   = ws + take(BN);
    int*   IDX  = (int*)(ws + take(BN * Kn));
    float* Z1   = ws + take(BN * 256);
    float* Z2   = ws + take(BN * 256);
    float* VMX  = ws + take(BN * 256);
    float* VMN  = ws + take(BN * 256);
    float* SSUM = ws + take(64 * 256);
    float* SSQ  = ws + take(64 * 256);
    float* BNS  = ws + take(256);
    float* BNB  = ws + take(256);
    float* WT   = ws + take(65536);
    float* FCT1 = ws + take(524288);
    float* FCT2 = ws + take(131072);
    float* X1   = ws + take(BN * 64);
    float* X2   = ws + take(BN * 64);
    float* X3   = ws + take(BN * 128);
    float* X4   = ws + take(BN * 256);
    float* GV   = ws + take((size_t)Bb * 1024);

    run_layer<3, 64>(points, W1, g1, b1, X1, DIST, XX, IDX, Z1, Z2, VMX, VMN, SSUM, SSQ, BNS, BNB, WT, big, stream);
    run_layer<64, 64>(X1, W2, g2, b2, X2, DIST, XX, IDX, Z1, Z2, VMX, VMN, SSUM, SSQ, BNS, BNB, WT, big, stream);
    run_layer<64, 128>(X2, W3, g3, b3, X3, DIST, XX, IDX, Z1, Z2, VMX, VMN, SSUM, SSQ, BNS, BNB, WT, big, stream);
    run_layer<128, 256>(X3, W4, g4, b4, X4, DIST, XX, IDX, Z1, Z2, VMX, VMN, SSUM, SSQ, BNS, BNB, WT, big, stream);

    pool_kernel<<<64, 256, 0, stream>>>(X1, X2, X3, X4, GV);
    transpose_kernel<<<(512 * 1024 + 255) / 256, 256, 0, stream>>>(fc1_w, FCT1, 512, 1024);
    transpose_kernel<<<(256 * 512 + 255) / 256, 256, 0, stream>>>(fc2_w, FCT2, 256, 512);
    head_kernel<<<Bb, 256, 0, stream>>>(GV, FCT1, fc1_b, ln1g, ln1b, FCT2, fc2_b, ln2g, ln2b,
                                        (float*)d_out);
}

// Round 4
// 963.545 us; speedup vs baseline: 2.2787x; 1.1455x over previous
//
#include <hip/hip_runtime.h>
#include <cstdint>
#include <cstddef>

static constexpr int Bb = 8;
static constexpr int Nn = 2048;
static constexpr int Kn = 20;
static constexpr float EPSV = 1e-5f;

// ---------------------------------------------------------------- utilities

// blocks 0..63: xx[i] = ||x_i||^2 ; blocks 64..191: zero 32K floats of zp
__global__ void sqnorm_zero_kernel(const float* __restrict__ x, float* __restrict__ xx, int C,
                                   float* __restrict__ zp) {
    int blk = blockIdx.x;
    if (blk < 64) {
        int i = blk * 256 + threadIdx.x;
        const float* xr = x + (size_t)i * C;
        float s = 0.f;
        for (int c = 0; c < C; ++c) { float v = xr[c]; s += v * v; }
        xx[i] = s;
    } else {
        zp[(blk - 64) * 256 + threadIdx.x] = 0.f;
    }
}

// out[c*R + r] = in[r*Cc + c]   (small matrices, once per launch)
__global__ void transpose_kernel(const float* __restrict__ in, float* __restrict__ out,
                                 int R, int Cc) {
    int i = blockIdx.x * 256 + threadIdx.x;
    if (i < R * Cc) {
        int r = i / Cc, c = i % Cc;
        out[(size_t)c * R + r] = in[i];
    }
}

// ------------------------------------------------ pairwise sq-dist (tiled gram)
// 128x128 tile per block, 8x8 per thread, transposed LDS (As[cc][i]) so
// fragments load as ds_read_b128. B is split into BsA/BsB (stride 68) so the
// 16 tx-groups alias banks 2-way (free) instead of 4-way.

template<int C>
__global__ __launch_bounds__(256, 2)
void gram_dist_kernel(const float* __restrict__ x, const float* __restrict__ xx,
                      float* __restrict__ dist, int b0, size_t dstride) {
    constexpr int CT = (C < 16) ? C : 16;
    const int b = b0 + blockIdx.z;
    const int i0 = blockIdx.y * 128, j0 = blockIdx.x * 128;
    const int tid = threadIdx.x;
    const int tx = tid & 15, ty = tid >> 4;
    __shared__ float As[CT][136];
    __shared__ float BsA[CT][68];
    __shared__ float BsB[CT][68];
    float acc[8][8] = {};
    const float* xb = x + (size_t)b * Nn * C;

    const int si = tid & 127;         // staging row
    const int half = tid >> 7;        // 0..1
    // B-side scatter target for row si: element (c, si) -> bbase[c*68]
    float* bbase = ((si & 4) ? &BsB[0][0] : &BsA[0][0]) + (((si >> 3) << 2) | (si & 3));

    for (int c0 = 0; c0 < C; c0 += CT) {
        if constexpr (CT == 16) {
            const float* ra = xb + (size_t)(i0 + si) * C + c0 + half * 8;
            const float* rb = xb + (size_t)(j0 + si) * C + c0 + half * 8;
            float4 a0 = *(const float4*)ra;
            float4 a1 = *(const float4*)(ra + 4);
            float4 bq0 = *(const float4*)rb;
            float4 bq1 = *(const float4*)(rb + 4);
            const int cb = half * 8;
            As[cb + 0][si] = a0.x; As[cb + 1][si] = a0.y;
            As[cb + 2][si] = a0.z; As[cb + 3][si] = a0.w;
            As[cb + 4][si] = a1.x; As[cb + 5][si] = a1.y;
            As[cb + 6][si] = a1.z; As[cb + 7][si] = a1.w;
            bbase[(cb + 0) * 68] = bq0.x; bbase[(cb + 1) * 68] = bq0.y;
            bbase[(cb + 2) * 68] = bq0.z; bbase[(cb + 3) * 68] = bq0.w;
            bbase[(cb + 4) * 68] = bq1.x; bbase[(cb + 5) * 68] = bq1.y;
            bbase[(cb + 6) * 68] = bq1.z; bbase[(cb + 7) * 68] = bq1.w;
        } else {
            if (half == 0) {
                const float* ra = xb + (size_t)(i0 + si) * C + c0;
#pragma unroll
                for (int c = 0; c < CT; ++c) As[c][si] = ra[c];
            } else {
                const float* rb = xb + (size_t)(j0 + si) * C + c0;
#pragma unroll
                for (int c = 0; c < CT; ++c) bbase[c * 68] = rb[c];
            }
        }
        __syncthreads();
#pragma unroll
        for (int cc = 0; cc < CT; ++cc) {
            float a[8], bv[8];
            *(float4*)&a[0]  = *(const float4*)&As[cc][ty * 8];
            *(float4*)&a[4]  = *(const float4*)&As[cc][ty * 8 + 4];
            *(float4*)&bv[0] = *(const float4*)&BsA[cc][tx * 4];
            *(float4*)&bv[4] = *(const float4*)&BsB[cc][tx * 4];
#pragma unroll
            for (int u = 0; u < 8; ++u)
#pragma unroll
                for (int v = 0; v < 8; ++v)
                    acc[u][v] = fmaf(a[u], bv[v], acc[u][v]);
        }
        __syncthreads();
    }

    const float* xxb = xx + (size_t)b * Nn;
    float xi[8], xj[8];
#pragma unroll
    for (int u = 0; u < 8; ++u) xi[u] = xxb[i0 + ty * 8 + u];
#pragma unroll
    for (int v = 0; v < 8; ++v) xj[v] = xxb[j0 + tx * 8 + v];
    float* db = dist + (size_t)blockIdx.z * dstride;
#pragma unroll
    for (int u = 0; u < 8; ++u) {
        float* row = db + (size_t)(i0 + ty * 8 + u) * Nn + (j0 + tx * 8);
        float4 o0, o1;
        o0.x = xi[u] + xj[0] - 2.f * acc[u][0];
        o0.y = xi[u] + xj[1] - 2.f * acc[u][1];
        o0.z = xi[u] + xj[2] - 2.f * acc[u][2];
        o0.w = xi[u] + xj[3] - 2.f * acc[u][3];
        o1.x = xi[u] + xj[4] - 2.f * acc[u][4];
        o1.y = xi[u] + xj[5] - 2.f * acc[u][5];
        o1.z = xi[u] + xj[6] - 2.f * acc[u][6];
        o1.w = xi[u] + xj[7] - 2.f * acc[u][7];
        *(float4*)row = o0;
        *(float4*)(row + 4) = o1;
    }
}

// ------------------------------------------------------- top-k (k=20 smallest)
// One wave (64 lanes) per row; no __syncthreads. Per-lane static sorted top-4
// with rare mask-based refill; 20 rounds of (val,idx)-lexicographic butterfly.

__device__ __forceinline__ bool lex_less(float v1, int j1, float v2, int j2) {
    return v1 < v2 || (v1 == v2 && j1 < j2);
}

__device__ __forceinline__ void top4_build(const float4* __restrict__ dr4, int lane,
                                           unsigned xmask,
                                           float& tv0, int& tj0, int& ts0,
                                           float& tv1, int& tj1, int& ts1,
                                           float& tv2, int& tj2, int& ts2,
                                           float& tv3, int& tj3, int& ts3) {
    tv0 = tv1 = tv2 = tv3 = 3e38f;
    tj0 = tj1 = tj2 = tj3 = 1 << 30;
    ts0 = ts1 = ts2 = ts3 = 0;
#pragma unroll
    for (int q = 0; q < 8; ++q) {
        float4 f = dr4[q * 64 + lane];
        float vv[4] = {f.x, f.y, f.z, f.w};
#pragma unroll
        for (int c = 0; c < 4; ++c) {
            int s = q * 4 + c;
            if ((xmask >> s) & 1u) continue;
            int j = (q * 64 + lane) * 4 + c;
            float v = vv[c];
            if (lex_less(v, j, tv3, tj3)) {
                tv3 = v; tj3 = j; ts3 = s;
                if (lex_less(tv3, tj3, tv2, tj2)) {
                    float fv = tv2; int fj = tj2, fs = ts2;
                    tv2 = tv3; tj2 = tj3; ts2 = ts3; tv3 = fv; tj3 = fj; ts3 = fs;
                }
                if (lex_less(tv2, tj2, tv1, tj1)) {
                    float fv = tv1; int fj = tj1, fs = ts1;
                    tv1 = tv2; tj1 = tj2; ts1 = ts2; tv2 = fv; tj2 = fj; ts2 = fs;
                }
                if (lex_less(tv1, tj1, tv0, tj0)) {
                    float fv = tv0; int fj = tj0, fs = ts0;
                    tv0 = tv1; tj0 = tj1; ts0 = ts1; tv1 = fv; tj1 = fj; ts1 = fs;
                }
            }
        }
    }
}

__global__ void topk_kernel(const float* __restrict__ dist, int* __restrict__ idxo,
                            int b0, size_t dstride, int rows_per_batch_only) {
    const int w = threadIdx.x >> 6;               // wave within block (4 waves)
    const int lane = threadIdx.x & 63;
    const int lin = blockIdx.x * 4 + w;           // row id
    int bz, i;
    if (rows_per_batch_only) { bz = 0; i = lin; }
    else { bz = lin >> 11; i = lin & (Nn - 1); }
    const int b = b0 + bz;
    const float4* dr4 = (const float4*)(dist + (size_t)bz * dstride + (size_t)i * Nn);

    float tv0, tv1, tv2, tv3;
    int tj0, tj1, tj2, tj3, ts0, ts1, ts2, ts3;
    unsigned xmask = 0;
    top4_build(dr4, lane, 0u, tv0, tj0, ts0, tv1, tj1, ts1, tv2, tj2, ts2, tv3, tj3, ts3);
    int cnt = 0;

    int* orow = idxo + ((size_t)b * Nn + i) * Kn;
    for (int t = 0; t < Kn; ++t) {
        float bv = tv0; int bj = tj0;
#pragma unroll
        for (int off = 1; off < 64; off <<= 1) {
            float ov = __shfl_xor(bv, off);
            int oj = __shfl_xor(bj, off);
            if (lex_less(ov, oj, bv, bj)) { bv = ov; bj = oj; }
        }
        if (lane == 0) orow[t] = bj;
        if (tj0 == bj) {                           // this lane owned the winner
            xmask |= 1u << ts0;
            tv0 = tv1; tj0 = tj1; ts0 = ts1;
            tv1 = tv2; tj1 = tj2; ts1 = ts2;
            tv2 = tv3; tj2 = tj3; ts2 = ts3;
            tv3 = 3e38f; tj3 = 1 << 30; ts3 = 0;
            if (++cnt == 4) {                      // rare: lane exhausted its top-4
                top4_build(dr4, lane, xmask, tv0, tj0, ts0, tv1, tj1, ts1,
                           tv2, tj2, ts2, tv3, tj3, ts3);
                cnt = 0;
            }
        }
    }
}

// ------------------------------------- per-point projections Z1=X Wl^T, Z2=X Wr^T

template<int C, int O>
__global__ void z_kernel(const float* __restrict__ x, const float* __restrict__ wt,
                         float* __restrict__ z1, float* __restrict__ z2) {
    constexpr int TP = 16;
    constexpr int G = 256 / O;
    constexpr int PP = TP / G;
    const int p0 = blockIdx.x * TP;
    const int tid = threadIdx.x;
    const int oo = tid % O;
    const int g = tid / O;
    __shared__ float xs[TP][(C < 4) ? 4 : C];
    for (int e = tid; e < TP * C; e += 256) {
        int p = e / C, c = e % C;
        xs[p][c] = x[(size_t)(p0 + p) * C + c];
    }
    __syncthreads();
    float a1[PP], a2[PP];
#pragma unroll
    for (int p = 0; p < PP; ++p) { a1[p] = 0.f; a2[p] = 0.f; }
    if constexpr (C % 4 == 0) {
        for (int c = 0; c < C; c += 4) {
            float w1[4], w2[4];
#pragma unroll
            for (int q = 0; q < 4; ++q) {
                w1[q] = wt[(size_t)(c + q) * O + oo];
                w2[q] = wt[(size_t)(C + c + q) * O + oo];
            }
#pragma unroll
            for (int p = 0; p < PP; ++p) {
                const float4 xv = *(const float4*)(&xs[g * PP + p][c]);
                a1[p] = fmaf(xv.w, w1[3], fmaf(xv.z, w1[2], fmaf(xv.y, w1[1], fmaf(xv.x, w1[0], a1[p]))));
                a2[p] = fmaf(xv.w, w2[3], fmaf(xv.z, w2[2], fmaf(xv.y, w2[1], fmaf(xv.x, w2[0], a2[p]))));
            }
        }
    } else {
        for (int c = 0; c < C; ++c) {
            float w1 = wt[(size_t)c * O + oo];
            float w2 = wt[(size_t)(C + c) * O + oo];
#pragma unroll
            for (int p = 0; p < PP; ++p) {
                float xv = xs[g * PP + p][c];
                a1[p] = fmaf(xv, w1, a1[p]);
                a2[p] = fmaf(xv, w2, a2[p]);
            }
        }
    }
#pragma unroll
    for (int p = 0; p < PP; ++p) {
        size_t row = (size_t)(p0 + g * PP + p) * O + oo;
        z1[row] = a1[p];
        z2[row] = a2[p];
    }
}

// -------------------- gather edges, max/min over k + BN partial sums (per channel)

template<int O>
__global__ void edge_stats_kernel(const float* __restrict__ z1, const float* __restrict__ z2,
                                  const int* __restrict__ idx,
                                  float* __restrict__ vmax, float* __restrict__ vmin,
                                  float* __restrict__ ssum, float* __restrict__ ssq) {
    constexpr int G = 256 / O;
    constexpr int KK = Kn / G;          // 20 / {1,2,4}
    const int bi = blockIdx.x;          // 0 .. B*N-1
    const int b = bi >> 11;
    const int tid = threadIdx.x;
    const int oo = tid % O;
    const int g = tid / O;
    __shared__ int jl[Kn];
    if (tid < Kn) jl[tid] = idx[(size_t)bi * Kn + tid];
    __syncthreads();
    const float zi1 = z1[(size_t)bi * O + oo];
    const float a = z2[(size_t)bi * O + oo] - zi1;
    float mx = -3e38f, mn = 3e38f, s = 0.f, s2 = 0.f;
    for (int kk = 0; kk < KK; ++kk) {
        int j = jl[g * KK + kk];
        float v = z1[((size_t)b * Nn + j) * O + oo] + a;
        mx = fmaxf(mx, v);
        mn = fminf(mn, v);
        s += v;
        s2 = fmaf(v, v, s2);
    }
    if constexpr (G > 1) {
        __shared__ float smx[256], smn[256], ssm[256], sqq[256];
        smx[tid] = mx; smn[tid] = mn; ssm[tid] = s; sqq[tid] = s2;
        __syncthreads();
        if (tid < O) {
#pragma unroll
            for (int gg = 1; gg < G; ++gg) {
                mx = fmaxf(mx, smx[gg * O + oo]);
                mn = fminf(mn, smn[gg * O + oo]);
                s += ssm[gg * O + oo];
                s2 += sqq[gg * O + oo];
            }
        }
    }
    if (tid < O) {
        vmax[(size_t)bi * O + oo] = mx;
        vmin[(size_t)bi * O + oo] = mn;
        int slot = bi & 63;
        atomicAdd(&ssum[slot * O + oo], s);
        atomicAdd(&ssq[slot * O + oo], s2);
    }
}

__global__ void bn_finalize_kernel(const float* __restrict__ ssum, const float* __restrict__ ssq,
                                   const float* __restrict__ gamma, const float* __restrict__ beta,
                                   float* __restrict__ scale, float* __restrict__ shift, int O) {
    int o = threadIdx.x;
    if (o >= O) return;
    float s = 0.f, q = 0.f;
    for (int sl = 0; sl < 64; ++sl) { s += ssum[sl * O + o]; q += ssq[sl * O + o]; }
    const float cnt = (float)Bb * (float)Nn * (float)Kn;
    float mu = s / cnt;
    float var = q / cnt - mu * mu;
    float sc = gamma[o] / sqrtf(var + EPSV);
    scale[o] = sc;
    shift[o] = beta[o] - mu * sc;
}

// ---------------- BN-apply + relu + per-chunk pooling partials (max & sum)
// grid: (16 n-chunks, 8 b); 128 points per block. Replaces apply+pool read.

template<int O>
__global__ void apply_pool_kernel(const float* __restrict__ vmax, const float* __restrict__ vmin,
                                  const float* __restrict__ scale, const float* __restrict__ shift,
                                  float* __restrict__ xout,
                                  float* __restrict__ pmax, float* __restrict__ psum, int obase) {
    constexpr int G = 256 / O;          // 4,4,2,1
    constexpr int S = 128 / G;          // points per thread
    const int chunk = blockIdx.x;
    const int b = blockIdx.y;
    const int tid = threadIdx.x;
    const int oo = tid % O;
    const int g = tid / O;
    const int n0 = chunk * 128;
    const float sc = scale[oo], sh = shift[oo];
    float pm = -3e38f, ps = 0.f;
    for (int s = 0; s < S; ++s) {
        int n = n0 + g + s * G;
        size_t idx = ((size_t)b * Nn + n) * O + oo;
        float v = (sc >= 0.f) ? vmax[idx] : vmin[idx];   // max/min commute w/ monotone affine
        float r = fmaxf(fmaf(v, sc, sh), 0.f);
        xout[idx] = r;
        pm = fmaxf(pm, r);
        ps += r;
    }
    if constexpr (G > 1) {
        __shared__ float sm[256], ss[256];
        sm[tid] = pm; ss[tid] = ps;
        __syncthreads();
        if (g == 0) {
#pragma unroll
            for (int gg = 1; gg < G; ++gg) {
                pm = fmaxf(pm, sm[gg * O + oo]);
                ps += ss[gg * O + oo];
            }
        }
    }
    if (g == 0) {
        size_t p = ((size_t)b * 16 + chunk) * 512 + obase + oo;
        pmax[p] = pm;
        psum[p] = ps;
    }
}

__global__ void pool_finalize_kernel(const float* __restrict__ pmax, const float* __restrict__ psum,
                                     float* __restrict__ gv) {
    const int b = blockIdx.x;
    const int c = threadIdx.x;          // 512 threads
    float mx = -3e38f, s = 0.f;
    for (int ch = 0; ch < 16; ++ch) {
        size_t p = ((size_t)b * 16 + ch) * 512 + c;
        mx = fmaxf(mx, pmax[p]);
        s += psum[p];
    }
    gv[b * 1024 + c] = mx;
    gv[b * 1024 + 512 + c] = s * (1.f / (float)Nn);
}

// ------------------------------------------------------------------- MLP head

__global__ void head_kernel(const float* __restrict__ gv,
                            const float* __restrict__ fct1, const float* __restrict__ fc1b,
                            const float* __restrict__ ln1g, const float* __restrict__ ln1b,
                            const float* __restrict__ fct2, const float* __restrict__ fc2b,
                            const float* __restrict__ ln2g, const float* __restrict__ ln2b,
                            float* __restrict__ out) {
    const int b = blockIdx.x;
    const int tid = threadIdx.x;
    __shared__ float gx[1024];
    __shared__ float hh[512];
    __shared__ float red[256];
    for (int e = tid; e < 1024; e += 256) gx[e] = gv[b * 1024 + e];
    __syncthreads();
    float h0 = fc1b[tid], h1 = fc1b[tid + 256];
    for (int c = 0; c < 1024; ++c) {
        float gc = gx[c];
        h0 = fmaf(gc, fct1[(size_t)c * 512 + tid], h0);
        h1 = fmaf(gc, fct1[(size_t)c * 512 + tid + 256], h1);
    }
    // LayerNorm over 512
    red[tid] = h0 + h1;
    __syncthreads();
    for (int st = 128; st > 0; st >>= 1) { if (tid < st) red[tid] += red[tid + st]; __syncthreads(); }
    float mu = red[0] * (1.f / 512.f);
    __syncthreads();
    float d0 = h0 - mu, d1 = h1 - mu;
    red[tid] = d0 * d0 + d1 * d1;
    __syncthreads();
    for (int st = 128; st > 0; st >>= 1) { if (tid < st) red[tid] += red[tid + st]; __syncthreads(); }
    float rs = 1.f / sqrtf(red[0] * (1.f / 512.f) + EPSV);
    __syncthreads();
    hh[tid]       = fmaxf(d0 * rs * ln1g[tid] + ln1b[tid], 0.f);
    hh[tid + 256] = fmaxf(d1 * rs * ln1g[tid + 256] + ln1b[tid + 256], 0.f);
    __syncthreads();
    float z = fc2b[tid];
    for (int c = 0; c < 512; ++c) z = fmaf(hh[c], fct2[(size_t)c * 256 + tid], z);
    red[tid] = z;
    __syncthreads();
    for (int st = 128; st > 0; st >>= 1) { if (tid < st) red[tid] += red[tid + st]; __syncthreads(); }
    float mu2 = red[0] * (1.f / 256.f);
    __syncthreads();
    float dz = z - mu2;
    red[tid] = dz * dz;
    __syncthreads();
    for (int st = 128; st > 0; st >>= 1) { if (tid < st) red[tid] += red[tid + st]; __syncthreads(); }
    float rs2 = 1.f / sqrtf(red[0] * (1.f / 256.f) + EPSV);
    out[b * 256 + tid] = dz * rs2 * ln2g[tid] + ln2b[tid];
}

// --------------------------------------------------------------- layer driver

template<int C, int O>
static void run_layer(const float* x, const float* W, const float* gamma, const float* beta,
                      float* xout, float* DIST, float* XX, int* IDX, float* Z1, float* Z2,
                      float* VMX, float* VMN, float* SSUM, float* SSQ, float* BNS, float* BNB,
                      float* WT, float* PMAX, float* PSUM, int obase, bool big,
                      hipStream_t stream) {
    sqnorm_zero_kernel<<<192, 256, 0, stream>>>(x, XX, C, SSUM);  // SSUM+SSQ contiguous 32K
    transpose_kernel<<<(O * 2 * C + 255) / 256, 256, 0, stream>>>(W, WT, O, 2 * C);
    z_kernel<C, O><<<Bb * Nn / 16, 256, 0, stream>>>(x, WT, Z1, Z2);
    if (big) {
        gram_dist_kernel<C><<<dim3(Nn / 128, Nn / 128, Bb), 256, 0, stream>>>(x, XX, DIST, 0, (size_t)Nn * Nn);
        topk_kernel<<<Bb * Nn / 4, 256, 0, stream>>>(DIST, IDX, 0, (size_t)Nn * Nn, 0);
    } else {
        for (int b = 0; b < Bb; ++b) {
            gram_dist_kernel<C><<<dim3(Nn / 128, Nn / 128, 1), 256, 0, stream>>>(x, XX, DIST, b, 0);
            topk_kernel<<<Nn / 4, 256, 0, stream>>>(DIST, IDX, b, 0, 1);
        }
    }
    edge_stats_kernel<O><<<Bb * Nn, 256, 0, stream>>>(Z1, Z2, IDX, VMX, VMN, SSUM, SSQ);
    bn_finalize_kernel<<<1, 256, 0, stream>>>(SSUM, SSQ, gamma, beta, BNS, BNB, O);
    apply_pool_kernel<O><<<dim3(16, 8), 256, 0, stream>>>(VMX, VMN, BNS, BNB, xout, PMAX, PSUM, obase);
}

extern "C" void kernel_launch(void* const* d_in, const int* in_sizes, int n_in,
                              void* d_out, int out_size, void* d_ws, size_t ws_size,
                              hipStream_t stream) {
    const float* points = (const float*)d_in[0];
    const float* W1 = (const float*)d_in[1];
    const float* g1 = (const float*)d_in[2];
    const float* b1 = (const float*)d_in[3];
    const float* W2 = (const float*)d_in[4];
    const float* g2 = (const float*)d_in[5];
    const float* b2 = (const float*)d_in[6];
    const float* W3 = (const float*)d_in[7];
    const float* g3 = (const float*)d_in[8];
    const float* b3 = (const float*)d_in[9];
    const float* W4 = (const float*)d_in[10];
    const float* g4 = (const float*)d_in[11];
    const float* b4 = (const float*)d_in[12];
    const float* fc1_w = (const float*)d_in[13];
    const float* fc1_b = (const float*)d_in[14];
    const float* ln1g = (const float*)d_in[15];
    const float* ln1b = (const float*)d_in[16];
    const float* fc2_w = (const float*)d_in[17];
    const float* fc2_b = (const float*)d_in[18];
    const float* ln2g = (const float*)d_in[19];
    const float* ln2b = (const float*)d_in[20];
    // d_in[21] = k (always 20 for this problem)

    float* ws = (float*)d_ws;
    const size_t BN = (size_t)Bb * Nn;
    const bool big = ws_size >= (size_t)59826688 * 4;   // full-batch dist buffer fits?

    size_t off = 0;
    auto take = [&](size_t n) { size_t o = off; off += n; return o; };
    float* DIST = ws + take(big ? (size_t)Bb * Nn * Nn : (size_t)Nn * Nn);
    float* XX   = ws + take(BN);
    int*   IDX  = (int*)(ws + take(BN * Kn));
    float* Z1   = ws + take(BN * 256);
    float* Z2   = ws + take(BN * 256);
    float* VMX  = ws + take(BN * 256);
    float* VMN  = ws + take(BN * 256);
    float* SSUM = ws + take(64 * 256);
    float* SSQ  = ws + take(64 * 256);
    float* BNS  = ws + take(256);
    float* BNB  = ws + take(256);
    float* WT   = ws + take(65536);
    float* FCT1 = ws + take(524288);
    float* FCT2 = ws + take(131072);
    float* X1   = ws + take(BN * 64);
    float* X2   = ws + take(BN * 64);
    float* X3   = ws + take(BN * 128);
    float* X4   = ws + take(BN * 256);
    float* GV   = ws + take((size_t)Bb * 1024);
    float* PMAX = ws + take((size_t)Bb * 16 * 512);
    float* PSUM = ws + take((size_t)Bb * 16 * 512);

    run_layer<3, 64>(points, W1, g1, b1, X1, DIST, XX, IDX, Z1, Z2, VMX, VMN, SSUM, SSQ, BNS, BNB, WT, PMAX, PSUM, 0, big, stream);
    run_layer<64, 64>(X1, W2, g2, b2, X2, DIST, XX, IDX, Z1, Z2, VMX, VMN, SSUM, SSQ, BNS, BNB, WT, PMAX, PSUM, 64, big, stream);
    run_layer<64, 128>(X2, W3, g3, b3, X3, DIST, XX, IDX, Z1, Z2, VMX, VMN, SSUM, SSQ, BNS, BNB, WT, PMAX, PSUM, 128, big, stream);
    run_layer<128, 256>(X3, W4, g4, b4, X4, DIST, XX, IDX, Z1, Z2, VMX, VMN, SSUM, SSQ, BNS, BNB, WT, PMAX, PSUM, 256, big, stream);

    pool_finalize_kernel<<<Bb, 512, 0, stream>>>(PMAX, PSUM, GV);
    transpose_kernel<<<(512 * 1024 + 255) / 256, 256, 0, stream>>>(fc1_w, FCT1, 512, 1024);
    transpose_kernel<<<(256 * 512 + 255) / 256, 256, 0, stream>>>(fc2_w, FCT2, 256, 512);
    head_kernel<<<Bb, 256, 0, stream>>>(GV, FCT1, fc1_b, ln1g, ln1b, FCT2, fc2_b, ln2g, ln2b,
                                        (float*)d_out);
}